// Round 8
// baseline (109.576 us; speedup 1.0000x reference)
//
#include <hip/hip_runtime.h>

// ContrastiveEmbeddingLoss, N=8192, D=128, C=100, margin=1.
// loss = [ sum_{y_i!=y_j} d_ij + N*margin + sum_{same,i!=j} max(margin-d_ij,0) ] / N^2
//   dissim = 2*sum_c SQ_c*(N - n_c) - 2*||S||^2 + 2*SSsum
//     SQ_c = sum_{i in c}||x_i||^2,  S = sum_i x_i,  SSsum = sum_c sum_{a,b in c} x_a.x_b
// Only same-class pairs (~N^2/100) need explicit d -> per-class fp16 MFMA Gram.
//
// 3 graph nodes (R6's in-kernel grid barrier: 3.4x WORSE, agent-scope spin
// ~140us -- never reintroduce):
//   rank (1 block, 16-way replicated LDS histogram): rank[], cnt[]; zeroes ws.
//   scan (1024 blocks x 8 rows, R5's best-measured config): coalesced x pass.
//   gram (800 blocks): MFMA Gram hinge; last block (done-counter) finalizes.

#define N_ROWS 8192
#define DIM    128
#define NCLS   100
#define CAP    224            // Binom(8192,0.01): mean 82, sd 9 -> +15 sigma
#define SCB    1024           // scan blocks (8 rows each)
#define GBPC   8              // gram blocks per class
#define GRAMB  (NCLS * GBPC)  // 800
#define NREP   8              // atomic replication for Scol/SQc
#define HREP   16             // LDS histogram replicas in rank_kernel
#define ZWORDS (NREP * DIM + NREP * NCLS + 3)   // Scol8+SQc8+Hsum+SSsum+done

typedef _Float16 half8  __attribute__((ext_vector_type(8)));
typedef _Float16 half4v __attribute__((ext_vector_type(4)));
typedef float    float4v __attribute__((ext_vector_type(4)));

// ---- Kernel 0 (1 block, 1024 thr): ranks via replicated LDS histogram ------
__global__ __launch_bounds__(1024) void rank_kernel(
    const int* __restrict__ y, int* __restrict__ cnt, int* __restrict__ rank,
    float* __restrict__ zregion)
{
    const int tid = threadIdx.x;
    __shared__ int lcnt[HREP][NCLS];   // 6.4 KB, 16 replicas -> contention /16
    __shared__ int lbase[NCLS], pfx[128];

    for (int i = tid; i < ZWORDS; i += 1024) zregion[i] = 0.f;   // control ws
    for (int i = tid; i < HREP * NCLS; i += 1024) ((int*)lcnt)[i] = 0;
    __syncthreads();

    const int rep = tid & (HREP - 1);
    int yv[8], ord[8];
    #pragma unroll
    for (int k = 0; k < 8; ++k) yv[k] = y[tid + k * 1024];       // coalesced
    #pragma unroll
    for (int k = 0; k < 8; ++k) ord[k] = atomicAdd(&lcnt[rep][yv[k]], 1);
    __syncthreads();

    // Per-class: replica exclusive offsets (serial 16-step) + class total.
    if (tid < NCLS) {
        int run = 0;
        #pragma unroll
        for (int r = 0; r < HREP; ++r) {
            int v = lcnt[r][tid];
            lcnt[r][tid] = run;       // becomes replica base within class
            run += v;
        }
        cnt[tid] = run;
    }
    if (tid < 128) pfx[tid] = 0;
    __syncthreads();
    if (tid < NCLS) pfx[tid] = lcnt[HREP - 1][tid] +            // = total
                               ((tid < NCLS) ? 0 : 0);
    // NOTE: lcnt[HREP-1][c] is base of last replica, not total; recompute:
    if (tid < NCLS) pfx[tid] = cnt[tid];
    __syncthreads();
    for (int off = 1; off < 128; off <<= 1) {                   // Hillis-Steele
        int v = 0;
        if (tid < 128) { v = pfx[tid]; if (tid >= off) v += pfx[tid - off]; }
        __syncthreads();
        if (tid < 128) pfx[tid] = v;
        __syncthreads();
    }
    if (tid < NCLS) lbase[tid] = pfx[tid] - cnt[tid];           // exclusive
    __syncthreads();
    #pragma unroll
    for (int k = 0; k < 8; ++k) {
        const int c = yv[k];
        rank[tid + k * 1024] = lbase[c] + lcnt[rep][c] + ord[k];
    }
}

// ---- Kernel 1 (1024 blocks, 8 rows): coalesced pass, all stores free --------
__global__ __launch_bounds__(256) void scan_kernel(
    const float* __restrict__ x, const int* __restrict__ y,
    const int* __restrict__ rank,
    _Float16* __restrict__ gh, float* __restrict__ sqg,
    float* __restrict__ Scol8, float* __restrict__ SQc8)
{
    const int b = blockIdx.x, tid = threadIdx.x;
    const int l = tid & 31, g = tid >> 5;            // 32 lanes/row, 8 rows/blk
    const int r = b * 8 + g;
    const int rep = b & (NREP - 1);
    const float4* x4 = (const float4*)x;
    __shared__ float4 colred[256];

    float4 v = x4[r * 32 + l];                       // fully coalesced
    float s = v.x*v.x + v.y*v.y + v.z*v.z + v.w*v.w;
    s += __shfl_xor(s, 1);  s += __shfl_xor(s, 2);  s += __shfl_xor(s, 4);
    s += __shfl_xor(s, 8);  s += __shfl_xor(s, 16);  // row sqnorm
    const int c = y[r];                              // uniform per group
    const int p = rank[r];                           // precomputed placement
    if (p < CAP) {                                   // never false in practice
        half4v h;
        h[0] = (_Float16)v.x; h[1] = (_Float16)v.y;
        h[2] = (_Float16)v.z; h[3] = (_Float16)v.w;
        *(half4v*)(gh + (size_t)(c * CAP + p) * DIM + l * 4) = h;
        if (l == 0) sqg[c * CAP + p] = s;
    }
    if (l == 0) atomicAdd(&SQc8[rep * NCLS + c], s);

    colred[tid] = v;
    __syncthreads();
    if (tid < 32) {
        float4 a = colred[tid];
        #pragma unroll
        for (int gg = 1; gg < 8; ++gg) {
            float4 t = colred[tid + 32 * gg];
            a.x += t.x; a.y += t.y; a.z += t.z; a.w += t.w;
        }
        float* dst = Scol8 + rep * DIM;
        atomicAdd(&dst[4 * tid + 0], a.x);
        atomicAdd(&dst[4 * tid + 1], a.y);
        atomicAdd(&dst[4 * tid + 2], a.z);
        atomicAdd(&dst[4 * tid + 3], a.w);
    }
}

// ---- Kernel 2 (800 blocks): per-class MFMA Gram hinge + fused finalize ------
__global__ __launch_bounds__(256) void gram_kernel(
    const _Float16* __restrict__ gh, const float* __restrict__ sqg,
    const int* __restrict__ cnt,
    const float* __restrict__ Scol8, const float* __restrict__ SQc8,
    float* __restrict__ Hsum, float* __restrict__ SSsum,
    int* __restrict__ done, float* __restrict__ out)
{
    const int c = blockIdx.x >> 3, qq = blockIdx.x & 7, tid = threadIdx.x;
    __shared__ float wred[8];
    __shared__ int   lastFlag;

    const int mtrue = cnt[c];
    const int m = mtrue < CAP ? mtrue : CAP;
    const int ntiles = (m + 15) >> 4;
    const int ntp = ntiles * (ntiles + 1) / 2;       // ~21 for m~82

    const int wave = tid >> 6, lane = tid & 63;
    const int lr = lane & 15, q = lane >> 4;
    float hacc = 0.f, dsum = 0.f;
    const _Float16* base = gh + (size_t)c * CAP * DIM;
    const float* sqb_ = sqg + c * CAP;

    for (int tp = qq * 4 + wave; tp < ntp; tp += 32) {   // <=1 pair/wave typ.
        int ta = 0, rem = tp;
        while (rem >= ntiles - ta) { rem -= ntiles - ta; ++ta; }
        const int tb = ta + rem;
        // Pad rows hold benign fp16 poison (no NaN/Inf); outputs gated below.
        const half8* ap = (const half8*)(base + (ta * 16 + lr) * DIM + q * 8);
        const half8* bp = (const half8*)(base + (tb * 16 + lr) * DIM + q * 8);
        float4v acc = {0.f, 0.f, 0.f, 0.f};
        #pragma unroll
        for (int kb = 0; kb < 4; ++kb)               // +32 halves per K block
            acc = __builtin_amdgcn_mfma_f32_16x16x32_f16(ap[kb * 4], bp[kb * 4], acc, 0, 0, 0);
        const float w = (ta == tb) ? 1.f : 2.f;
        const int bb = tb * 16 + lr;                 // C/D col = lane & 15
        const float sqb = (bb < m) ? sqb_[bb] : 0.f;
        #pragma unroll
        for (int i = 0; i < 4; ++i) {
            const int a = ta * 16 + q * 4 + i;       // C/D row = quad*4 + reg
            if (a < m && bb < m) {
                const float dot = acc[i];
                dsum += w * dot;                     // includes diagonal a==bb
                if (a != bb) {
                    float d = fmaxf(sqb_[a] + sqb - 2.f * dot, 0.f);
                    hacc += w * fmaxf(1.f - d, 0.f);
                }
            }
        }
    }
    #pragma unroll
    for (int off = 32; off > 0; off >>= 1) {
        hacc += __shfl_xor(hacc, off);
        dsum += __shfl_xor(dsum, off);
    }
    if (lane == 0) { wred[wave] = hacc; wred[4 + wave] = dsum; }
    __syncthreads();
    if (tid == 0) {
        float h = wred[0] + wred[1] + wred[2] + wred[3];
        float d = wred[4] + wred[5] + wred[6] + wred[7];
        if (h != 0.f) atomicAdd(Hsum, h);
        if (d != 0.f) atomicAdd(SSsum, d);
        __threadfence();                             // release before counting
        int p = atomicAdd(done, 1);
        lastFlag = (p == GRAMB - 1);
    }
    __syncthreads();
    if (!lastFlag) return;

    // ---------------- fused finalize (last-arriving block only) ------------
    __threadfence();                                 // acquire others' results
    const double Nf = (double)N_ROWS;
    double contrib = 0.0;
    if (tid < DIM) {                                 // -2 ||S||^2
        float sc = 0.f;
        #pragma unroll
        for (int k = 0; k < NREP; ++k) sc += Scol8[k * DIM + tid];
        contrib -= 2.0 * (double)sc * (double)sc;
    }
    if (tid < NCLS) {                                // 2 SQ_c (N - n_c)
        float qv = 0.f;
        #pragma unroll
        for (int k = 0; k < NREP; ++k) qv += SQc8[k * NCLS + tid];
        contrib += 2.0 * (double)qv * (Nf - (double)cnt[tid]);
    }
    if (tid == 0) {
        float H  = __hip_atomic_load(Hsum,  __ATOMIC_RELAXED, __HIP_MEMORY_SCOPE_AGENT);
        float SS = __hip_atomic_load(SSsum, __ATOMIC_RELAXED, __HIP_MEMORY_SCOPE_AGENT);
        contrib += 2.0 * (double)SS + (double)H + Nf * 1.0 /* N*margin */;
    }
    __shared__ double dred[256];
    dred[tid] = contrib;
    __syncthreads();
    for (int s = 128; s > 0; s >>= 1) {
        if (tid < s) dred[tid] += dred[tid + s];
        __syncthreads();
    }
    if (tid == 0) out[0] = (float)(dred[0] / (Nf * Nf));
}

extern "C" void kernel_launch(void* const* d_in, const int* in_sizes, int n_in,
                              void* d_out, int out_size, void* d_ws, size_t ws_size,
                              hipStream_t stream) {
    const float* x = (const float*)d_in[0];
    const int*   y = (const int*)d_in[1];

    _Float16* gh = (_Float16*)d_ws;                         // 100*224*128 fp16 = 5.73 MB
    float* sqg   = (float*)(gh + (size_t)NCLS * CAP * DIM); // 100*224
    int*   rank  = (int*)(sqg + NCLS * CAP);                // 8192
    // ---- control region (zeroed by rank_kernel): ----
    float* Scol8 = (float*)(rank + N_ROWS);  // NREP*128
    float* SQc8  = Scol8 + NREP * DIM;       // NREP*100
    float* Hsum  = SQc8 + NREP * NCLS;       // 1
    float* SSsum = Hsum + 1;                 // 1
    int*   done  = (int*)(SSsum + 1);        // 1   (end of ZWORDS region)
    int*   cnt   = done + 1;                 // 100 (fully written by rank)

    rank_kernel<<<1,     1024, 0, stream>>>(y, cnt, rank, Scol8);
    scan_kernel<<<SCB,   256,  0, stream>>>(x, y, rank, gh, sqg, Scol8, SQc8);
    gram_kernel<<<GRAMB, 256,  0, stream>>>(gh, sqg, cnt, Scol8, SQc8,
                                            Hsum, SSsum, done, (float*)d_out);
}

// Round 9
// 98.896 us; speedup vs baseline: 1.1080x; 1.1080x over previous
//
#include <hip/hip_runtime.h>

// ContrastiveEmbeddingLoss, N=8192, D=128, C=100, margin=1.
// loss = [ sum_{y_i!=y_j} d_ij + N*margin + sum_{same,i!=j} max(margin-d_ij,0) ] / N^2
//   dissim = 2*sum_c SQ_c*(N - n_c) - 2*||S||^2 + 2*SSsum
//     SQ_c = sum_{i in c}||x_i||^2,  S = sum_i x_i,  SSsum = sum_c sum_{a,b in c} x_a.x_b
// Only same-class pairs (~N^2/100) need explicit d -> per-class fp16 MFMA Gram.
//
// Measured session notes: R6's in-kernel grid barrier = 3.4x WORSE (agent-scope
// spin ~140us) -- never reintroduce. Single-block rank (R7/R8) robustly worse
// than parallel 32-block version (one CU + serial tail blocks the chain).
//
// 3 graph nodes, no global atomics on the critical path:
//   hist (32 blocks):  per-region histogram hist[32][100] (LDS atomics only) +
//                      intra-region ranks; zeroes the 1.9KB control region.
//   scan (1024 blocks): coalesced x pass; global slot = shfl-prefix of hist
//                      column + intra rank (loads overlap the x row loads).
//   gram (800 blocks): MFMA Gram hinge; n_c derived from hist via shfl-sum;
//                      last block (done-counter) runs the double finalize.

#define N_ROWS 8192
#define DIM    128
#define NCLS   100
#define CAP    224            // Binom(8192,0.01): mean 82, sd 9 -> +15 sigma
#define HB     32             // hist blocks (256 rows each)
#define SCB    1024           // scan blocks (8 rows each)
#define GBPC   8              // gram blocks per class
#define GRAMB  (NCLS * GBPC)  // 800
#define NREP   8              // atomic replication for Scol/SQc
#define ZWORDS (NREP * DIM + NREP * NCLS + 3)   // Scol8+SQc8+Hsum+SSsum+done

typedef _Float16 half8  __attribute__((ext_vector_type(8)));
typedef _Float16 half4v __attribute__((ext_vector_type(4)));
typedef float    float4v __attribute__((ext_vector_type(4)));

// ---- Kernel 0 (32 blocks): region histograms + intra ranks, zero control ----
__global__ __launch_bounds__(256) void hist_kernel(
    const int* __restrict__ y, int* __restrict__ hist,
    int* __restrict__ rankIntra, float* __restrict__ zregion)
{
    const int b = blockIdx.x, tid = threadIdx.x;
    __shared__ int lcnt[NCLS];

    {   // zero the 1927-word control region, one word per thread (blocks 0-7)
        const int i = b * 256 + tid;
        if (i < ZWORDS) zregion[i] = 0.f;
    }
    if (tid < NCLS) lcnt[tid] = 0;
    __syncthreads();
    const int r = b * 256 + tid;
    const int c = y[r];
    rankIntra[r] = atomicAdd(&lcnt[c], 1);     // ~2.5-way avg LDS contention
    __syncthreads();
    if (tid < NCLS) hist[b * NCLS + tid] = lcnt[tid];
}

// ---- Kernel 1 (1024 blocks, 8 rows): coalesced pass, all stores free --------
__global__ __launch_bounds__(256) void scan_kernel(
    const float* __restrict__ x, const int* __restrict__ y,
    const int* __restrict__ hist, const int* __restrict__ rankIntra,
    _Float16* __restrict__ gh, float* __restrict__ sqg,
    float* __restrict__ Scol8, float* __restrict__ SQc8)
{
    const int b = blockIdx.x, tid = threadIdx.x;
    const int l = tid & 31, g = tid >> 5;            // 32 lanes/row, 8 rows/blk
    const int r = b * 8 + g;
    const int rep = b & (NREP - 1);
    const float4* x4 = (const float4*)x;
    __shared__ float4 colred[256];

    float4 v = x4[r * 32 + l];                       // fully coalesced
    const int c  = y[r];                             // broadcast within group
    const int ab = r >> 8;                           // hist region of row r
    // class base = sum of hist[a][c] for a < ab: one load per lane, shfl-sum.
    int hv = (l < ab) ? hist[l * NCLS + c] : 0;
    #pragma unroll
    for (int off = 1; off < 32; off <<= 1) hv += __shfl_xor(hv, off, 32);
    const int p = hv + rankIntra[r];                 // global slot in class c

    float s = v.x*v.x + v.y*v.y + v.z*v.z + v.w*v.w;
    s += __shfl_xor(s, 1);  s += __shfl_xor(s, 2);  s += __shfl_xor(s, 4);
    s += __shfl_xor(s, 8);  s += __shfl_xor(s, 16);  // row sqnorm
    if (p < CAP) {                                   // never false in practice
        half4v h;
        h[0] = (_Float16)v.x; h[1] = (_Float16)v.y;
        h[2] = (_Float16)v.z; h[3] = (_Float16)v.w;
        *(half4v*)(gh + (size_t)(c * CAP + p) * DIM + l * 4) = h;
        if (l == 0) sqg[c * CAP + p] = s;
    }
    if (l == 0) atomicAdd(&SQc8[rep * NCLS + c], s);

    colred[tid] = v;
    __syncthreads();
    if (tid < 32) {
        float4 a = colred[tid];
        #pragma unroll
        for (int gg = 1; gg < 8; ++gg) {
            float4 t = colred[tid + 32 * gg];
            a.x += t.x; a.y += t.y; a.z += t.z; a.w += t.w;
        }
        float* dst = Scol8 + rep * DIM;
        atomicAdd(&dst[4 * tid + 0], a.x);
        atomicAdd(&dst[4 * tid + 1], a.y);
        atomicAdd(&dst[4 * tid + 2], a.z);
        atomicAdd(&dst[4 * tid + 3], a.w);
    }
}

// ---- Kernel 2 (800 blocks): per-class MFMA Gram hinge + fused finalize ------
__global__ __launch_bounds__(256) void gram_kernel(
    const _Float16* __restrict__ gh, const float* __restrict__ sqg,
    const int* __restrict__ hist,
    const float* __restrict__ Scol8, const float* __restrict__ SQc8,
    float* __restrict__ Hsum, float* __restrict__ SSsum,
    int* __restrict__ done, float* __restrict__ out)
{
    const int c = blockIdx.x >> 3, qq = blockIdx.x & 7, tid = threadIdx.x;
    __shared__ float wred[8];
    __shared__ int   lastFlag;

    const int wave = tid >> 6, lane = tid & 63;
    // n_c = sum over 32 regions of hist[a][c]: 1 load/lane + 6 shfl rounds.
    int mt = (lane < HB) ? hist[lane * NCLS + c] : 0;
    #pragma unroll
    for (int off = 1; off < 64; off <<= 1) mt += __shfl_xor(mt, off);
    const int mtrue = mt;
    const int m = mtrue < CAP ? mtrue : CAP;
    const int ntiles = (m + 15) >> 4;
    const int ntp = ntiles * (ntiles + 1) / 2;       // ~21 for m~82

    const int lr = lane & 15, q = lane >> 4;
    float hacc = 0.f, dsum = 0.f;
    const _Float16* base = gh + (size_t)c * CAP * DIM;
    const float* sqb_ = sqg + c * CAP;

    for (int tp = qq * 4 + wave; tp < ntp; tp += 32) {   // <=1 pair/wave typ.
        int ta = 0, rem = tp;
        while (rem >= ntiles - ta) { rem -= ntiles - ta; ++ta; }
        const int tb = ta + rem;
        // Pad rows hold benign fp16 poison (no NaN/Inf); outputs gated below.
        const half8* ap = (const half8*)(base + (ta * 16 + lr) * DIM + q * 8);
        const half8* bp = (const half8*)(base + (tb * 16 + lr) * DIM + q * 8);
        float4v acc = {0.f, 0.f, 0.f, 0.f};
        #pragma unroll
        for (int kb = 0; kb < 4; ++kb)               // +32 halves per K block
            acc = __builtin_amdgcn_mfma_f32_16x16x32_f16(ap[kb * 4], bp[kb * 4], acc, 0, 0, 0);
        const float w = (ta == tb) ? 1.f : 2.f;
        const int bb = tb * 16 + lr;                 // C/D col = lane & 15
        const float sqb = (bb < m) ? sqb_[bb] : 0.f;
        #pragma unroll
        for (int i = 0; i < 4; ++i) {
            const int a = ta * 16 + q * 4 + i;       // C/D row = quad*4 + reg
            if (a < m && bb < m) {
                const float dot = acc[i];
                dsum += w * dot;                     // includes diagonal a==bb
                if (a != bb) {
                    float d = fmaxf(sqb_[a] + sqb - 2.f * dot, 0.f);
                    hacc += w * fmaxf(1.f - d, 0.f);
                }
            }
        }
    }
    #pragma unroll
    for (int off = 32; off > 0; off >>= 1) {
        hacc += __shfl_xor(hacc, off);
        dsum += __shfl_xor(dsum, off);
    }
    if (lane == 0) { wred[wave] = hacc; wred[4 + wave] = dsum; }
    __syncthreads();
    if (tid == 0) {
        float h = wred[0] + wred[1] + wred[2] + wred[3];
        float d = wred[4] + wred[5] + wred[6] + wred[7];
        if (h != 0.f) atomicAdd(Hsum, h);
        if (d != 0.f) atomicAdd(SSsum, d);
        __threadfence();                             // release before counting
        int p = atomicAdd(done, 1);
        lastFlag = (p == GRAMB - 1);
    }
    __syncthreads();
    if (!lastFlag) return;

    // ---------------- fused finalize (last-arriving block only) ------------
    __threadfence();                                 // acquire others' results
    const double Nf = (double)N_ROWS;
    double contrib = 0.0;
    if (tid < DIM) {                                 // -2 ||S||^2
        float sc = 0.f;
        #pragma unroll
        for (int k = 0; k < NREP; ++k) sc += Scol8[k * DIM + tid];
        contrib -= 2.0 * (double)sc * (double)sc;
    }
    if (tid < NCLS) {                                // 2 SQ_c (N - n_c)
        float qv = 0.f;
        #pragma unroll
        for (int k = 0; k < NREP; ++k) qv += SQc8[k * NCLS + tid];
        int nc = 0;
        for (int a = 0; a < HB; ++a) nc += hist[a * NCLS + tid];
        contrib += 2.0 * (double)qv * (Nf - (double)nc);
    }
    if (tid == 0) {
        float H  = __hip_atomic_load(Hsum,  __ATOMIC_RELAXED, __HIP_MEMORY_SCOPE_AGENT);
        float SS = __hip_atomic_load(SSsum, __ATOMIC_RELAXED, __HIP_MEMORY_SCOPE_AGENT);
        contrib += 2.0 * (double)SS + (double)H + Nf * 1.0 /* N*margin */;
    }
    __shared__ double dred[256];
    dred[tid] = contrib;
    __syncthreads();
    for (int s = 128; s > 0; s >>= 1) {
        if (tid < s) dred[tid] += dred[tid + s];
        __syncthreads();
    }
    if (tid == 0) out[0] = (float)(dred[0] / (Nf * Nf));
}

extern "C" void kernel_launch(void* const* d_in, const int* in_sizes, int n_in,
                              void* d_out, int out_size, void* d_ws, size_t ws_size,
                              hipStream_t stream) {
    const float* x = (const float*)d_in[0];
    const int*   y = (const int*)d_in[1];

    _Float16* gh    = (_Float16*)d_ws;                         // 100*224*128 fp16 = 5.73 MB
    float* sqg      = (float*)(gh + (size_t)NCLS * CAP * DIM); // 100*224
    int*   rankIntra= (int*)(sqg + NCLS * CAP);                // 8192
    int*   hist     = rankIntra + N_ROWS;                      // 32*100
    // ---- control region (zeroed by hist_kernel): ----
    float* Scol8 = (float*)(hist + HB * NCLS);  // NREP*128
    float* SQc8  = Scol8 + NREP * DIM;          // NREP*100
    float* Hsum  = SQc8 + NREP * NCLS;          // 1
    float* SSsum = Hsum + 1;                    // 1
    int*   done  = (int*)(SSsum + 1);           // 1  (end of ZWORDS region)

    hist_kernel<<<HB,    256, 0, stream>>>(y, hist, rankIntra, Scol8);
    scan_kernel<<<SCB,   256, 0, stream>>>(x, y, hist, rankIntra, gh, sqg, Scol8, SQc8);
    gram_kernel<<<GRAMB, 256, 0, stream>>>(gh, sqg, hist, Scol8, SQc8,
                                           Hsum, SSsum, done, (float*)d_out);
}